// Round 6
// baseline (416.119 us; speedup 1.0000x reference)
//
#include <hip/hip_runtime.h>
#include <math.h>

#define B_DIM 512
#define K_DIM 2048
#define N_DIM 4096
#define BRN 16
#define NUM_TARGET 4096

#define THR_MIN 0.5
#define THR_MAX 2.0
#define REFRACT 2.0f
#define LN_EPS 1e-5

// ---- GEMM: dend[B,N] = X[B,K] * W[N,K]^T + b, f64 accumulation -------------
// f32 tiles in LDS; convert to f64 in the inner loop; 64x64x32 tiles,
// 256 threads, 4x4 micro-tile. Output split hi/lo f32 so the fused kernel
// can reconstruct the exact f64 dend.
#define BM 64
#define BN 64
#define BK 32
#define LPAD 68

__global__ __launch_bounds__(256) void gemm_f64acc_kernel(
    const float* __restrict__ X,    // [B, K]
    const float* __restrict__ W,    // [N, K]
    const float* __restrict__ bias, // [N]
    float* __restrict__ dhi,        // [B, N]  (new_mem slice)
    float* __restrict__ dlo)        // [B, N]  (spike slice)
{
    __shared__ float As[BK][LPAD];  // [k][m]
    __shared__ float Bs[BK][LPAD];  // [k][n]

    const int t = threadIdx.x;
    const int row0 = blockIdx.x * BM;
    const int col0 = blockIdx.y * BN;
    const int tn = t & 15;
    const int tm = t >> 4;

    double acc[4][4] = {{0,0,0,0},{0,0,0,0},{0,0,0,0},{0,0,0,0}};

    for (int k0 = 0; k0 < K_DIM; k0 += BK) {
        #pragma unroll
        for (int i = 0; i < 2; ++i) {
            int lin = t + i * 256;
            int r   = lin >> 3;
            int k4  = lin & 7;
            float4 a = *(const float4*)&X[(row0 + r) * K_DIM + k0 + k4 * 4];
            As[k4*4+0][r] = a.x; As[k4*4+1][r] = a.y;
            As[k4*4+2][r] = a.z; As[k4*4+3][r] = a.w;
            float4 w = *(const float4*)&W[(col0 + r) * K_DIM + k0 + k4 * 4];
            Bs[k4*4+0][r] = w.x; Bs[k4*4+1][r] = w.y;
            Bs[k4*4+2][r] = w.z; Bs[k4*4+3][r] = w.w;
        }
        __syncthreads();

        #pragma unroll
        for (int k = 0; k < BK; ++k) {
            float4 a = *(const float4*)&As[k][tm * 4];
            float4 b = *(const float4*)&Bs[k][tn * 4];
            double ax = (double)a.x, ay = (double)a.y, az = (double)a.z, aw = (double)a.w;
            double bx = (double)b.x, by = (double)b.y, bz = (double)b.z, bw = (double)b.w;
            acc[0][0] += ax * bx; acc[0][1] += ax * by; acc[0][2] += ax * bz; acc[0][3] += ax * bw;
            acc[1][0] += ay * bx; acc[1][1] += ay * by; acc[1][2] += ay * bz; acc[1][3] += ay * bw;
            acc[2][0] += az * bx; acc[2][1] += az * by; acc[2][2] += az * bz; acc[2][3] += az * bw;
            acc[3][0] += aw * bx; acc[3][1] += aw * by; acc[3][2] += aw * bz; acc[3][3] += aw * bw;
        }
        __syncthreads();
    }

    float4 bv = *(const float4*)&bias[col0 + tn * 4];
    double bvd[4] = {(double)bv.x, (double)bv.y, (double)bv.z, (double)bv.w};
    #pragma unroll
    for (int i = 0; i < 4; ++i) {
        int row = row0 + tm * 4 + i;
        float4 hv, lv;
        double v0 = acc[i][0] + bvd[0];
        double v1 = acc[i][1] + bvd[1];
        double v2 = acc[i][2] + bvd[2];
        double v3 = acc[i][3] + bvd[3];
        hv.x = (float)v0; lv.x = (float)(v0 - (double)hv.x);
        hv.y = (float)v1; lv.y = (float)(v1 - (double)hv.y);
        hv.z = (float)v2; lv.z = (float)(v2 - (double)hv.z);
        hv.w = (float)v3; lv.w = (float)(v3 - (double)hv.w);
        *(float4*)&dhi[row * N_DIM + col0 + tn * 4] = hv;
        *(float4*)&dlo[row * N_DIM + col0 + tn * 4] = lv;
    }
}

// ------------- fused LayerNorm + soma + axon scatter, one block per row -----
__device__ inline float pow09(int d) {
    switch (d) {
        case 0: return 1.0f;
        case 1: return 0.9f;
        case 2: return 0.81f;
        case 3: return 0.729f;
        case 4: return 0.6561f;
        case 5: return 0.59049f;
        default: return powf(0.9f, (float)d);
    }
}

__global__ __launch_bounds__(256) void fused_row_kernel(
    const float* __restrict__ dhi,    // [B,N]  (aliases mem_o)
    const float* __restrict__ dlo,    // [B,N]  (aliases spike_o)
    const float* __restrict__ mem_i,
    const float* __restrict__ ref_i,
    const float* __restrict__ gamma,
    const float* __restrict__ beta,
    const float* __restrict__ thr_p,
    const float* __restrict__ dec_p,
    const float* __restrict__ att,    // [N,BR]
    const int*   __restrict__ tgt,    // [N,BR]
    const int*   __restrict__ dly,    // [N,BR]
    float* __restrict__ axon_o,       // [B,NUM_TARGET]
    float* __restrict__ spike_o,      // [B,N]
    float* __restrict__ mem_o,        // [B,N]
    float* __restrict__ ref_o)        // [B,N]
{
    __shared__ double sm_d[N_DIM];        // 32 KB
    __shared__ float  sm_axon[NUM_TARGET];// 16 KB
    __shared__ double red[4];

    const int b = blockIdx.x;
    const int t = threadIdx.x;
    const int lane = t & 63;
    const int wv = t >> 6;
    const float* hrow = dhi + (size_t)b * N_DIM;
    const float* lrow = dlo + (size_t)b * N_DIM;

    for (int i = t; i < NUM_TARGET; i += 256) sm_axon[i] = 0.f;

    // stage exact f64 dend row in LDS + f64 partial sum
    double s = 0.0;
    #pragma unroll
    for (int j = 0; j < 4; ++j) {
        int i = t + j * 256;              // float4 index (1024 total)
        float4 h = ((const float4*)hrow)[i];
        float4 l = ((const float4*)lrow)[i];
        double d0 = (double)h.x + (double)l.x;
        double d1 = (double)h.y + (double)l.y;
        double d2 = (double)h.z + (double)l.z;
        double d3 = (double)h.w + (double)l.w;
        sm_d[i*4+0] = d0; sm_d[i*4+1] = d1;
        sm_d[i*4+2] = d2; sm_d[i*4+3] = d3;
        s += d0 + d1 + d2 + d3;
    }
    #pragma unroll
    for (int o = 32; o > 0; o >>= 1) s += __shfl_down(s, o, 64);
    if (lane == 0) red[wv] = s;
    __syncthreads();
    const double mu = (red[0] + red[1] + red[2] + red[3]) * (1.0 / 4096.0);

    double vs = 0.0;
    #pragma unroll
    for (int j = 0; j < 4; ++j) {
        int i = t + j * 256;
        double d0 = sm_d[i*4+0] - mu, d1 = sm_d[i*4+1] - mu;
        double d2 = sm_d[i*4+2] - mu, d3 = sm_d[i*4+3] - mu;
        vs += d0*d0 + d1*d1 + d2*d2 + d3*d3;
    }
    #pragma unroll
    for (int o = 32; o > 0; o >>= 1) vs += __shfl_down(vs, o, 64);
    __syncthreads();                      // everyone done reading red[] (mu)
    if (lane == 0) red[wv] = vs;
    __syncthreads();
    const double var = (red[0] + red[1] + red[2] + red[3]) * (1.0 / 4096.0);
    const double rstd = 1.0 / sqrt(var + LN_EPS);

    // soma (f64 decision path) + scatter (f32)
    for (int n = t; n < N_DIM; n += 256) {
        const int gi = b * N_DIM + n;
        double dv = (sm_d[n] - mu) * rstd * (double)gamma[n] + (double)beta[n];
        double d  = fmin(fmax((double)dec_p[n], 0.0), 1.0);
        double th = fmin(fmax((double)thr_p[n], THR_MIN), THR_MAX);
        float  rf = ref_i[gi];
        double nm = d * (double)mem_i[gi] + dv;
        bool   can = (rf <= 0.f);
        bool   fired = (nm >= th) && can;
        float  sp = fired ? 1.f : 0.f;
        if (fired) nm -= th;
        float  nr = fired ? REFRACT : fmaxf(rf - 1.f, 0.f);
        float  nmf = (float)nm;
        spike_o[gi] = sp;
        mem_o[gi]   = nmf;
        ref_o[gi]   = nr;

        float sig = sp + 0.1f * (1.0f / (1.0f + expf(-nmf)));
        const int base = n * BRN;
        #pragma unroll
        for (int j = 0; j < BRN; j += 4) {
            float4 a4 = *(const float4*)&att[base + j];
            int4  t4 = *(const int4*)&tgt[base + j];
            int4  d4 = *(const int4*)&dly[base + j];
            atomicAdd(&sm_axon[t4.x], sig * fminf(fmaxf(a4.x, 0.f), 1.f) * pow09(d4.x));
            atomicAdd(&sm_axon[t4.y], sig * fminf(fmaxf(a4.y, 0.f), 1.f) * pow09(d4.y));
            atomicAdd(&sm_axon[t4.z], sig * fminf(fmaxf(a4.z, 0.f), 1.f) * pow09(d4.z));
            atomicAdd(&sm_axon[t4.w], sig * fminf(fmaxf(a4.w, 0.f), 1.f) * pow09(d4.w));
        }
    }
    __syncthreads();

    float* arow = axon_o + (size_t)b * NUM_TARGET;
    for (int i = t; i < NUM_TARGET / 4; i += 256)
        ((float4*)arow)[i] = ((const float4*)sm_axon)[i];
}

extern "C" void kernel_launch(void* const* d_in, const int* in_sizes, int n_in,
                              void* d_out, int out_size, void* d_ws, size_t ws_size,
                              hipStream_t stream) {
    const float* x     = (const float*)d_in[0];
    const float* mem   = (const float*)d_in[1];
    const float* refr  = (const float*)d_in[2];
    const float* W     = (const float*)d_in[3];
    const float* bias  = (const float*)d_in[4];
    const float* gamma = (const float*)d_in[5];
    const float* beta  = (const float*)d_in[6];
    const float* thr   = (const float*)d_in[7];
    const float* dec   = (const float*)d_in[8];
    const float* att   = (const float*)d_in[9];
    const int*   tgt   = (const int*)d_in[10];
    const int*   dly   = (const int*)d_in[11];

    float* out   = (float*)d_out;
    const int SEC = B_DIM * N_DIM;
    float* axon  = out;
    float* spike = out + SEC;
    float* nmem  = out + 2 * SEC;
    float* nref  = out + 3 * SEC;
    float* dhi   = nmem;    // staged, overwritten with new_mem afterwards
    float* dlo   = spike;   // staged, overwritten with spike afterwards

    dim3 gg(B_DIM / BM, N_DIM / BN);
    gemm_f64acc_kernel<<<gg, 256, 0, stream>>>(x, W, bias, dhi, dlo);
    fused_row_kernel<<<B_DIM, 256, 0, stream>>>(dhi, dlo, mem, refr, gamma, beta,
                                                thr, dec, att, tgt, dly,
                                                axon, spike, nmem, nref);
}